// Round 7
// baseline (376.132 us; speedup 1.0000x reference)
//
#include <hip/hip_runtime.h>

// LNCC, separable 5-tap Gaussian (sigma=1), fused single pass.
// (N=2, C=1, D=160, H=192, W=224) fp32 -> scalar.
// R7: 2 px/thread (adjacent W cols) pair-packed; wide LDS ops (b128), pair-major
//     moment layout for v_pk_fma_f32; 320-thr blocks; R4 pipeline (1 barrier/slice).

#define NB 2
#define DD 160
#define HH 192
#define WW 224
#define SH 224
#define SD (224*192)
#define SN (224*192*160)

#define TW 32
#define TH 16
#define ROWS 20              // TH + 4
#define CP 16                // column pairs per tile
#define DCHUNK 20
#define NCHUNK (DD/DCHUNK)   // 8

#define K0 0.05448868f
#define K1 0.24420134f
#define K2 0.40261995f

struct F2 { float x, y; };
__device__ __forceinline__ F2 mkf2(float a, float b) { F2 r; r.x = a; r.y = b; return r; }

// 5-tap symmetric dot over F2 taps (per-component)
#define DOT5(p0,p1,p2,p3,p4) mkf2( \
    K0*((p0).x+(p4).x) + K1*((p1).x+(p3).x) + K2*(p2).x, \
    K0*((p0).y+(p4).y) + K1*((p1).y+(p3).y) + K2*(p2).y)

__global__ __launch_bounds__(320) void lncc_main(
    const float* __restrict__ A, const float* __restrict__ B,
    const float* __restrict__ M, double* __restrict__ acc)
{
    // raw (I,J) interleaved, cols 0..35 (2-col halo each side); row stride 288B (==8 banks, ok)
    __shared__ float2 sIJ[2][ROWS][36];
    // pair-major W-blur moments: [2c]=(bI.x,bI.y,bII.x,bII.y), [2c+1]=(bJ.x,bJ.y,bJJ.x,bJJ.y)
    __shared__ float4 wbP[2][ROWS][2*CP + 1];   // +1 float4 pad: stride 528B == 4 banks
    __shared__ float2 wbC2[2][ROWS][CP + 1];    // bIJ pairs; +1 pad: stride 136B == 2 banks
    __shared__ float  redL[5], redM[5];

    const int wt = blockIdx.x;           // 0..6
    const int ht = blockIdx.y;           // 0..11
    const int zz = blockIdx.z;           // 0..15
    const int n  = zz >> 3;
    const int dc = zz & 7;
    const int w0 = wt * TW, h0 = ht * TH, d0 = dc * DCHUNK;

    const float* __restrict__ Ai = A + (size_t)n * SN;
    const float* __restrict__ Bi = B + (size_t)n * SN;
    const float* __restrict__ Mi = M + (size_t)n * SN;

    const int tid = threadIdx.x;
    const int r   = tid >> 4;            // 0..19
    const int c   = tid & 15;            // 0..15 (column pair)

    const int gh  = h0 + r - 2;
    const bool hv = (unsigned)gh < (unsigned)HH;
    const int ghc = hv ? gh : 0;
    const int hwm = ghc * SH + (w0 + 2 * c);          // main float2 offset (even)
    const bool lh = (c == 0)  && (wt > 0);
    const bool rh = (c == 15) && (wt < 6);
    const bool anyh = (lh || rh) && hv;
    const int hwh = ghc * SH + (lh ? (w0 - 2) : (w0 + 32));
    const int mbase = (h0 + r) * SH + (w0 + 2 * c);

    // D-direction shift-register pipeline, pixel-pair per entry
    F2 pI0=mkf2(0,0),pI1=pI0,pI2=pI0,pI3=pI0;
    F2 pJ0=pI0,pJ1=pI0,pJ2=pI0,pJ3=pI0;
    F2 pC0=pI0,pC1=pI0,pC2=pI0,pC3=pI0;
    F2 pS0=pI0,pS1=pI0,pS2=pI0,pS3=pI0;
    F2 pT0=pI0,pT1=pI0,pT2=pI0,pT3=pI0;
    F2 accL=pI0, accM=pI0;

    // prefetch registers for slice staged at iteration k
    float2 nIa = {0,0}, nJa = {0,0}, nIh = {0,0}, nJh = {0,0};
    {
        const int dd = d0 - 2;
        if (dd >= 0) {
            const int dof = dd * SD;
            if (hv)   { nIa = *(const float2*)(Ai + dof + hwm); nJa = *(const float2*)(Bi + dof + hwm); }
            if (anyh) { nIh = *(const float2*)(Ai + dof + hwh); nJh = *(const float2*)(Bi + dof + hwh); }
        }
    }

    const int NIT = DCHUNK + 6;          // 26
    for (int k = 0; k < NIT; ++k) {
        const int pw = k & 1;
        const int px = pw ^ 1;

        // ---- W: stage prefetched raw slice ----
        if (k < DCHUNK + 4) {
            *(float4*)&sIJ[pw][r][2 + 2 * c] = make_float4(nIa.x, nJa.x, nIa.y, nJa.y);
            if (c == 0)       *(float4*)&sIJ[pw][r][0]  = make_float4(nIh.x, nJh.x, nIh.y, nJh.y);
            else if (c == 15) *(float4*)&sIJ[pw][r][34] = make_float4(nIh.x, nJh.x, nIh.y, nJh.y);
        }

        // ---- prefetch slice k+1 ----
        nIa = make_float2(0.f, 0.f); nJa = nIa; nIh = nIa; nJh = nIa;
        {
            const int dd = d0 - 1 + k;
            if ((k + 1 < DCHUNK + 4) && (dd >= 0) && (dd < DD)) {
                const int dof = dd * SD;
                if (hv)   { nIa = *(const float2*)(Ai + dof + hwm); nJa = *(const float2*)(Bi + dof + hwm); }
                if (anyh) { nIh = *(const float2*)(Ai + dof + hwh); nJh = *(const float2*)(Bi + dof + hwh); }
            }
        }
        // ---- mask pair for this iteration's output slice ----
        const int  dout = d0 - 6 + k;
        const bool outv = (k >= 6) && (r < TH);
        float2 mv = make_float2(0.f, 0.f);
        if (outv) mv = *(const float2*)(Mi + dout * SD + mbase);

        // ---- X: W-blur of slice staged last iteration ----
        if (k >= 1 && k <= DCHUNK + 4) {
            const float4* srow = (const float4*)&sIJ[px][r][0];
            const float4 q0 = srow[c];
            const float4 q1 = srow[c + 1];
            const float4 q2 = srow[c + 2];
            const float i0=q0.x, j0=q0.y, i1=q0.z, j1=q0.w;
            const float i2=q1.x, j2=q1.y, i3=q1.z, j3=q1.w;
            const float i4=q2.x, j4=q2.y, i5=q2.z, j5=q2.w;
            const float p0=i0*j0, p1=i1*j1, p2=i2*j2, p3=i3*j3, p4=i4*j4, p5=i5*j5;
            const float s0=i0*i0, s1=i1*i1, s2=i2*i2, s3=i3*i3, s4=i4*i4, s5=i5*i5;
            const float t0=j0*j0, t1=j1*j1, t2=j2*j2, t3=j3*j3, t4=j4*j4, t5=j5*j5;
            const F2 bi  = mkf2(K0*(i0+i4)+K1*(i1+i3)+K2*i2, K0*(i1+i5)+K1*(i2+i4)+K2*i3);
            const F2 bj  = mkf2(K0*(j0+j4)+K1*(j1+j3)+K2*j2, K0*(j1+j5)+K1*(j2+j4)+K2*j3);
            const F2 bij = mkf2(K0*(p0+p4)+K1*(p1+p3)+K2*p2, K0*(p1+p5)+K1*(p2+p4)+K2*p3);
            const F2 bii = mkf2(K0*(s0+s4)+K1*(s1+s3)+K2*s2, K0*(s1+s5)+K1*(s2+s4)+K2*s3);
            const F2 bjj = mkf2(K0*(t0+t4)+K1*(t1+t3)+K2*t2, K0*(t1+t5)+K1*(t2+t4)+K2*t3);
            wbP[px][r][2*c]     = make_float4(bi.x, bi.y, bii.x, bii.y);
            wbP[px][r][2*c + 1] = make_float4(bj.x, bj.y, bjj.x, bjj.y);
            wbC2[px][r][c]      = make_float2(bij.x, bij.y);
        }

        // ---- Y: H-blur of slice staged two iters ago + D-pipeline ----
        if (k >= 2 && r < TH) {
            F2 hI=mkf2(0,0), hII=hI, hJ=hI, hJJ=hI, hIJ=hI;
            const float kt[5] = {K0, K1, K2, K1, K0};
#pragma unroll
            for (int t = 0; t < 5; ++t) {
                const float4 u = wbP[pw][r + t][2*c];
                const float4 v = wbP[pw][r + t][2*c + 1];
                const float2 w = wbC2[pw][r + t][c];
                const float kk = kt[t];
                hI.x  = fmaf(kk, u.x, hI.x);  hI.y  = fmaf(kk, u.y, hI.y);
                hII.x = fmaf(kk, u.z, hII.x); hII.y = fmaf(kk, u.w, hII.y);
                hJ.x  = fmaf(kk, v.x, hJ.x);  hJ.y  = fmaf(kk, v.y, hJ.y);
                hJJ.x = fmaf(kk, v.z, hJJ.x); hJJ.y = fmaf(kk, v.w, hJJ.y);
                hIJ.x = fmaf(kk, w.x, hIJ.x); hIJ.y = fmaf(kk, w.y, hIJ.y);
            }

            if (outv) {
                const F2 bI  = DOT5(pI0, pI1, pI2, pI3, hI);
                const F2 bJ  = DOT5(pJ0, pJ1, pJ2, pJ3, hJ);
                const F2 bIJ = DOT5(pC0, pC1, pC2, pC3, hIJ);
                const F2 bII = DOT5(pS0, pS1, pS2, pS3, hII);
                const F2 bJJ = DOT5(pT0, pT1, pT2, pT3, hJJ);
                const float cx  = bIJ.x - bI.x * bJ.x;
                const float cy  = bIJ.y - bI.y * bJ.y;
                const float vIx = fmaxf(bII.x - bI.x * bI.x, 0.f) + 1e-5f;
                const float vIy = fmaxf(bII.y - bI.y * bI.y, 0.f) + 1e-5f;
                const float vJx = fmaxf(bJJ.x - bJ.x * bJ.x, 0.f) + 1e-5f;
                const float vJy = fmaxf(bJJ.y - bJ.y * bJ.y, 0.f) + 1e-5f;
                const float lx = 1.0f - cx * rsqrtf(vIx * vJx);
                const float ly = 1.0f - cy * rsqrtf(vIy * vJy);
                accL.x = fmaf(lx, mv.x, accL.x);
                accL.y = fmaf(ly, mv.y, accL.y);
                accM.x += mv.x;
                accM.y += mv.y;
            }

            pI0=pI1; pI1=pI2; pI2=pI3; pI3=hI;
            pJ0=pJ1; pJ1=pJ2; pJ2=pJ3; pJ3=hJ;
            pC0=pC1; pC1=pC2; pC2=pC3; pC3=hIJ;
            pS0=pS1; pS1=pS2; pS2=pS3; pS3=hII;
            pT0=pT1; pT1=pT2; pT2=pT3; pT3=hJJ;
        }

        __syncthreads();
    }

    // ---- reduction ----
    float aL = accL.x + accL.y;
    float aM = accM.x + accM.y;
#pragma unroll
    for (int off = 32; off > 0; off >>= 1) {
        aL += __shfl_down(aL, off, 64);
        aM += __shfl_down(aM, off, 64);
    }
    const int wave = tid >> 6;
    if ((tid & 63) == 0) { redL[wave] = aL; redM[wave] = aM; }
    __syncthreads();
    if (tid == 0) {
        float sL = 0.f, sM = 0.f;
#pragma unroll
        for (int kk = 0; kk < 5; ++kk) { sL += redL[kk]; sM += redM[kk]; }
        atomicAdd(&acc[0], (double)sL);
        atomicAdd(&acc[1], (double)sM);
    }
}

__global__ void lncc_final(const double* __restrict__ acc, float* __restrict__ out)
{
    out[0] = (float)(acc[0] / (acc[1] + 1e-8));
}

extern "C" void kernel_launch(void* const* d_in, const int* in_sizes, int n_in,
                              void* d_out, int out_size, void* d_ws, size_t ws_size,
                              hipStream_t stream)
{
    const float* A = (const float*)d_in[0];
    const float* B = (const float*)d_in[1];
    const float* M = (const float*)d_in[2];
    double* acc = (double*)d_ws;

    hipMemsetAsync(d_ws, 0, 2 * sizeof(double), stream);

    dim3 grid(WW / TW, HH / TH, NB * NCHUNK);   // (7, 12, 16) = 1344 blocks
    dim3 block(320);
    hipLaunchKernelGGL(lncc_main, grid, block, 0, stream, A, B, M, acc);
    hipLaunchKernelGGL(lncc_final, dim3(1), dim3(1), 0, stream, acc, (float*)d_out);
}

// Round 8
// 372.074 us; speedup vs baseline: 1.0109x; 1.0109x over previous
//
#include <hip/hip_runtime.h>

// LNCC, separable 5-tap Gaussian (sigma=1), fused single pass.
// (N=2, C=1, D=160, H=192, W=224) fp32 -> scalar.
// R8: R7's 2px/thread, but conflict-free LDS layout: moments split into
//     c-contiguous arrays (16B/lane b128, 8B/lane b64 patterns = R6's
//     measured-zero-conflict patterns). 320-thr blocks, 1 barrier/slice.

#define NB 2
#define DD 160
#define HH 192
#define WW 224
#define SH 224
#define SD (224*192)
#define SN (224*192*160)

#define TW 32
#define TH 16
#define ROWS 20              // TH + 4
#define CP 16                // column pairs per tile
#define DCHUNK 20
#define NCHUNK (DD/DCHUNK)   // 8

#define K0 0.05448868f
#define K1 0.24420134f
#define K2 0.40261995f

struct F2 { float x, y; };
__device__ __forceinline__ F2 mkf2(float a, float b) { F2 r; r.x = a; r.y = b; return r; }

#define DOT5(p0,p1,p2,p3,p4) mkf2( \
    K0*((p0).x+(p4).x) + K1*((p1).x+(p3).x) + K2*(p2).x, \
    K0*((p0).y+(p4).y) + K1*((p1).y+(p3).y) + K2*(p2).y)

__global__ __launch_bounds__(320) void lncc_main(
    const float* __restrict__ A, const float* __restrict__ B,
    const float* __restrict__ M, double* __restrict__ acc)
{
    // raw (I,J) interleaved pairs: [r][col] col 0..35 incl 2-col halo each side.
    __shared__ float2 sIJ[2][ROWS][36];          // 16B/lane contiguous writes/reads
    // W-blur moments, c-contiguous (conflict-free b128 at 16B/lane):
    __shared__ float4 wbI[2][ROWS][CP];          // (bI.x, bI.y, bII.x, bII.y)
    __shared__ float4 wbJ[2][ROWS][CP];          // (bJ.x, bJ.y, bJJ.x, bJJ.y)
    __shared__ float2 wbC2[2][ROWS][CP];         // (bIJ.x, bIJ.y)
    __shared__ float  redL[5], redM[5];

    const int wt = blockIdx.x;           // 0..6
    const int ht = blockIdx.y;           // 0..11
    const int zz = blockIdx.z;           // 0..15
    const int n  = zz >> 3;
    const int dc = zz & 7;
    const int w0 = wt * TW, h0 = ht * TH, d0 = dc * DCHUNK;

    const float* __restrict__ Ai = A + (size_t)n * SN;
    const float* __restrict__ Bi = B + (size_t)n * SN;
    const float* __restrict__ Mi = M + (size_t)n * SN;

    const int tid = threadIdx.x;
    const int r   = tid >> 4;            // 0..19
    const int c   = tid & 15;            // 0..15 (column pair)

    const int gh  = h0 + r - 2;
    const bool hv = (unsigned)gh < (unsigned)HH;
    const int ghc = hv ? gh : 0;
    const int hwm = ghc * SH + (w0 + 2 * c);
    const bool lh = (c == 0)  && (wt > 0);
    const bool rh = (c == 15) && (wt < 6);
    const bool anyh = (lh || rh) && hv;
    const int hwh = ghc * SH + (lh ? (w0 - 2) : (w0 + 32));
    const int mbase = (h0 + r) * SH + (w0 + 2 * c);

    // D-direction shift-register pipeline, pixel-pair per entry
    F2 pI0=mkf2(0,0),pI1=pI0,pI2=pI0,pI3=pI0;
    F2 pJ0=pI0,pJ1=pI0,pJ2=pI0,pJ3=pI0;
    F2 pC0=pI0,pC1=pI0,pC2=pI0,pC3=pI0;
    F2 pS0=pI0,pS1=pI0,pS2=pI0,pS3=pI0;
    F2 pT0=pI0,pT1=pI0,pT2=pI0,pT3=pI0;
    F2 accL=pI0, accM=pI0;

    float2 nIa = {0,0}, nJa = {0,0}, nIh = {0,0}, nJh = {0,0};
    {
        const int dd = d0 - 2;
        if (dd >= 0) {
            const int dof = dd * SD;
            if (hv)   { nIa = *(const float2*)(Ai + dof + hwm); nJa = *(const float2*)(Bi + dof + hwm); }
            if (anyh) { nIh = *(const float2*)(Ai + dof + hwh); nJh = *(const float2*)(Bi + dof + hwh); }
        }
    }

    const int NIT = DCHUNK + 6;          // 26
    for (int k = 0; k < NIT; ++k) {
        const int pw = k & 1;
        const int px = pw ^ 1;

        // ---- W: stage prefetched raw slice ----
        if (k < DCHUNK + 4) {
            *(float4*)&sIJ[pw][r][2 + 2 * c] = make_float4(nIa.x, nJa.x, nIa.y, nJa.y);
            if (c == 0)       *(float4*)&sIJ[pw][r][0]  = make_float4(nIh.x, nJh.x, nIh.y, nJh.y);
            else if (c == 15) *(float4*)&sIJ[pw][r][34] = make_float4(nIh.x, nJh.x, nIh.y, nJh.y);
        }

        // ---- prefetch slice k+1 ----
        nIa = make_float2(0.f, 0.f); nJa = nIa; nIh = nIa; nJh = nIa;
        {
            const int dd = d0 - 1 + k;
            if ((k + 1 < DCHUNK + 4) && (dd >= 0) && (dd < DD)) {
                const int dof = dd * SD;
                if (hv)   { nIa = *(const float2*)(Ai + dof + hwm); nJa = *(const float2*)(Bi + dof + hwm); }
                if (anyh) { nIh = *(const float2*)(Ai + dof + hwh); nJh = *(const float2*)(Bi + dof + hwh); }
            }
        }
        const int  dout = d0 - 6 + k;
        const bool outv = (k >= 6) && (r < TH);
        float2 mv = make_float2(0.f, 0.f);
        if (outv) mv = *(const float2*)(Mi + dout * SD + mbase);

        // ---- X: W-blur of slice staged last iteration ----
        if (k >= 1 && k <= DCHUNK + 4) {
            const float4* srow = (const float4*)&sIJ[px][r][0];
            const float4 q0 = srow[c];
            const float4 q1 = srow[c + 1];
            const float4 q2 = srow[c + 2];
            const float i0=q0.x, j0=q0.y, i1=q0.z, j1=q0.w;
            const float i2=q1.x, j2=q1.y, i3=q1.z, j3=q1.w;
            const float i4=q2.x, j4=q2.y, i5=q2.z, j5=q2.w;
            const float p0=i0*j0, p1=i1*j1, p2=i2*j2, p3=i3*j3, p4=i4*j4, p5=i5*j5;
            const float s0=i0*i0, s1=i1*i1, s2=i2*i2, s3=i3*i3, s4=i4*i4, s5=i5*i5;
            const float t0=j0*j0, t1=j1*j1, t2=j2*j2, t3=j3*j3, t4=j4*j4, t5=j5*j5;
            wbI[px][r][c]  = make_float4(
                K0*(i0+i4)+K1*(i1+i3)+K2*i2, K0*(i1+i5)+K1*(i2+i4)+K2*i3,
                K0*(s0+s4)+K1*(s1+s3)+K2*s2, K0*(s1+s5)+K1*(s2+s4)+K2*s3);
            wbJ[px][r][c]  = make_float4(
                K0*(j0+j4)+K1*(j1+j3)+K2*j2, K0*(j1+j5)+K1*(j2+j4)+K2*j3,
                K0*(t0+t4)+K1*(t1+t3)+K2*t2, K0*(t1+t5)+K1*(t2+t4)+K2*t3);
            wbC2[px][r][c] = make_float2(
                K0*(p0+p4)+K1*(p1+p3)+K2*p2, K0*(p1+p5)+K1*(p2+p4)+K2*p3);
        }

        // ---- Y: H-blur of slice staged two iters ago + D-pipeline ----
        if (k >= 2 && r < TH) {
            F2 hI=mkf2(0,0), hII=hI, hJ=hI, hJJ=hI, hIJ=hI;
            const float kt[5] = {K0, K1, K2, K1, K0};
#pragma unroll
            for (int t = 0; t < 5; ++t) {
                const float4 u = wbI[pw][r + t][c];
                const float4 v = wbJ[pw][r + t][c];
                const float2 w = wbC2[pw][r + t][c];
                const float kk = kt[t];
                hI.x  = fmaf(kk, u.x, hI.x);  hI.y  = fmaf(kk, u.y, hI.y);
                hII.x = fmaf(kk, u.z, hII.x); hII.y = fmaf(kk, u.w, hII.y);
                hJ.x  = fmaf(kk, v.x, hJ.x);  hJ.y  = fmaf(kk, v.y, hJ.y);
                hJJ.x = fmaf(kk, v.z, hJJ.x); hJJ.y = fmaf(kk, v.w, hJJ.y);
                hIJ.x = fmaf(kk, w.x, hIJ.x); hIJ.y = fmaf(kk, w.y, hIJ.y);
            }

            if (outv) {
                const F2 bI  = DOT5(pI0, pI1, pI2, pI3, hI);
                const F2 bJ  = DOT5(pJ0, pJ1, pJ2, pJ3, hJ);
                const F2 bIJ = DOT5(pC0, pC1, pC2, pC3, hIJ);
                const F2 bII = DOT5(pS0, pS1, pS2, pS3, hII);
                const F2 bJJ = DOT5(pT0, pT1, pT2, pT3, hJJ);
                const float cx  = bIJ.x - bI.x * bJ.x;
                const float cy  = bIJ.y - bI.y * bJ.y;
                const float vIx = fmaxf(bII.x - bI.x * bI.x, 0.f) + 1e-5f;
                const float vIy = fmaxf(bII.y - bI.y * bI.y, 0.f) + 1e-5f;
                const float vJx = fmaxf(bJJ.x - bJ.x * bJ.x, 0.f) + 1e-5f;
                const float vJy = fmaxf(bJJ.y - bJ.y * bJ.y, 0.f) + 1e-5f;
                const float lx = 1.0f - cx * rsqrtf(vIx * vJx);
                const float ly = 1.0f - cy * rsqrtf(vIy * vJy);
                accL.x = fmaf(lx, mv.x, accL.x);
                accL.y = fmaf(ly, mv.y, accL.y);
                accM.x += mv.x;
                accM.y += mv.y;
            }

            pI0=pI1; pI1=pI2; pI2=pI3; pI3=hI;
            pJ0=pJ1; pJ1=pJ2; pJ2=pJ3; pJ3=hJ;
            pC0=pC1; pC1=pC2; pC2=pC3; pC3=hIJ;
            pS0=pS1; pS1=pS2; pS2=pS3; pS3=hII;
            pT0=pT1; pT1=pT2; pT2=pT3; pT3=hJJ;
        }

        __syncthreads();
    }

    // ---- reduction ----
    float aL = accL.x + accL.y;
    float aM = accM.x + accM.y;
#pragma unroll
    for (int off = 32; off > 0; off >>= 1) {
        aL += __shfl_down(aL, off, 64);
        aM += __shfl_down(aM, off, 64);
    }
    const int wave = tid >> 6;
    if ((tid & 63) == 0) { redL[wave] = aL; redM[wave] = aM; }
    __syncthreads();
    if (tid == 0) {
        float sL = 0.f, sM = 0.f;
#pragma unroll
        for (int kk = 0; kk < 5; ++kk) { sL += redL[kk]; sM += redM[kk]; }
        atomicAdd(&acc[0], (double)sL);
        atomicAdd(&acc[1], (double)sM);
    }
}

__global__ void lncc_final(const double* __restrict__ acc, float* __restrict__ out)
{
    out[0] = (float)(acc[0] / (acc[1] + 1e-8));
}

extern "C" void kernel_launch(void* const* d_in, const int* in_sizes, int n_in,
                              void* d_out, int out_size, void* d_ws, size_t ws_size,
                              hipStream_t stream)
{
    const float* A = (const float*)d_in[0];
    const float* B = (const float*)d_in[1];
    const float* M = (const float*)d_in[2];
    double* acc = (double*)d_ws;

    hipMemsetAsync(d_ws, 0, 2 * sizeof(double), stream);

    dim3 grid(WW / TW, HH / TH, NB * NCHUNK);   // (7, 12, 16) = 1344 blocks
    dim3 block(320);
    hipLaunchKernelGGL(lncc_main, grid, block, 0, stream, A, B, M, acc);
    hipLaunchKernelGGL(lncc_final, dim3(1), dim3(1), 0, stream, acc, (float*)d_out);
}